// Round 2
// baseline (150.875 us; speedup 1.0000x reference)
//
#include <hip/hip_runtime.h>
#include <hip/hip_bf16.h>

typedef unsigned short u16;
typedef __attribute__((ext_vector_type(4))) float f32x4;
typedef __attribute__((ext_vector_type(8))) short s16x8;
typedef __attribute__((ext_vector_type(8))) unsigned short u16x8;

#define NEG_V (-1e9f)
#define EPS_V (1e-10f)

__device__ __forceinline__ u16 f2bf(float f) {
  unsigned u = __float_as_uint(f);
  u += 0x7fffu + ((u >> 16) & 1u);
  return (u16)(u >> 16);
}
__device__ __forceinline__ float bf2f(u16 h) {
  return __uint_as_float(((unsigned)h) << 16);
}
__device__ __forceinline__ float wred_max(float v) {
#pragma unroll
  for (int o = 32; o; o >>= 1) v = fmaxf(v, __shfl_xor(v, o));
  return v;
}
__device__ __forceinline__ float wred_sum(float v) {
#pragma unroll
  for (int o = 32; o; o >>= 1) v += __shfl_xor(v, o);
  return v;
}

// mask accessor robust to int32 / float32 / byte storage of the bool mask
__device__ __forceinline__ bool mask_at(const void* m, int kind, int idx) {
  if (kind == 0) return ((const int*)m)[idx] != 0;
  if (kind == 1) return ((const float*)m)[idx] != 0.0f;
  return ((const unsigned char*)m)[idx] != 0;
}

// ---------- K0a: exclusive scan of n_nodes -> seg_start[G+1] ----------
__global__ void k0_scan(const int* __restrict__ n_nodes, int* __restrict__ seg_start, int G) {
  if (blockIdx.x == 0 && threadIdx.x == 0) {
    int acc = 0;
    for (int g = 0; g < G; ++g) { seg_start[g] = acc; acc += n_nodes[g]; }
    seg_start[G] = acc;
  }
}

// ---------- K0c: detect action_mask storage dtype ----------
// Samples GA/4 dwords (== GA bytes: in-bounds whether the array is byte,
// int32, or float32). kind: 0=int32{0,1}, 1=float32{0,1.0f}, 2=byte.
__global__ __launch_bounds__(256) void k0_detect(const unsigned int* __restrict__ m,
                                                 int ndw, int* __restrict__ kind) {
  __shared__ int notInt, notFloat;
  if (threadIdx.x == 0) { notInt = 0; notFloat = 0; }
  __syncthreads();
  int li = 0, lf = 0;
  for (int i = threadIdx.x; i < ndw; i += 256) {
    unsigned v = m[i];
    if (v != 0u && v != 1u) li = 1;
    if (v != 0u && v != 0x3F800000u) lf = 1;
  }
  if (li) atomicOr(&notInt, 1);
  if (lf) atomicOr(&notFloat, 1);
  __syncthreads();
  if (threadIdx.x == 0) kind[0] = (!notInt) ? 0 : ((!notFloat) ? 1 : 2);
}

// ---------- K0b: pack weights to bf16 [320 cols][256 k] ----------
// cols 0..63 = W_agn rows, 64..127 = W_nga, 128..191 = W_qna, 192..255 = W_qan,
// col 256 = w_node, 257..319 = 0 (pad)
__global__ __launch_bounds__(256) void k0_pack(
    const float* __restrict__ w_node, const float* __restrict__ W_agn,
    const float* __restrict__ W_nga, const float* __restrict__ W_qna,
    const float* __restrict__ W_qan, u16* __restrict__ Wpack) {
  int idx = blockIdx.x * 256 + threadIdx.x;  // < 320*256
  int col = idx >> 8, k = idx & 255;
  float v = 0.f;
  if (col < 64) v = W_agn[col * 256 + k];
  else if (col < 128) v = W_nga[(col - 64) * 256 + k];
  else if (col < 192) v = W_qna[(col - 128) * 256 + k];
  else if (col < 256) v = W_qan[(col - 192) * 256 + k];
  else if (col == 256) v = w_node[k];
  Wpack[idx] = f2bf(v);
}

// ---------- K1: bf16 MFMA GEMM, 64 rows/block, 5 column chunks of 64 ----------
// outputs: agn (bf16 ws), nga (fp32 -> d_out p_n__a region), qna/qan (bf16 ws), nl (fp32 ws)
__global__ __launch_bounds__(256) void k1_gemm(
    const float* __restrict__ values, const u16* __restrict__ Wpack,
    const float* __restrict__ b_agn, const float* __restrict__ b_nga,
    const float* __restrict__ b_qna, const float* __restrict__ b_qan,
    u16* __restrict__ agn, float* __restrict__ nga,
    u16* __restrict__ qna, u16* __restrict__ qan,
    float* __restrict__ nl) {
  __shared__ u16 Va[64 * 256];  // bf16, XOR-swizzled: elem idx = m*256 + (k ^ ((m&7)<<3))
  __shared__ u16 Wb[64 * 256];
  const int t = threadIdx.x;
  const int row0 = blockIdx.x * 64;

  // stage values tile (fp32 -> bf16), swizzled
#pragma unroll
  for (int it = 0; it < 16; ++it) {
    int flat = t + 256 * it;          // 0..4095 float4-chunks
    int m = flat >> 6, fc = flat & 63;
    const float4 v = reinterpret_cast<const float4*>(values + (size_t)(row0 + m) * 256)[fc];
    ushort4 h;
    h.x = f2bf(v.x); h.y = f2bf(v.y); h.z = f2bf(v.z); h.w = f2bf(v.w);
    int idx = m * 256 + ((fc * 4) ^ ((m & 7) << 3));
    *reinterpret_cast<ushort4*>(&Va[idx]) = h;
  }

  const int lane = t & 63;
  const int wave = t >> 6;
  const int ln15 = lane & 15;
  const int kg = lane >> 4;
  const int ncol = wave * 16;

  for (int chunk = 0; chunk < 5; ++chunk) {
    __syncthreads();
    // stage weight chunk [64 n][256 k] bf16, swizzled
#pragma unroll
    for (int it = 0; it < 8; ++it) {
      int f = t + 256 * it;           // 0..2047 16B-chunks
      int n = f >> 5, kc = f & 31;
      u16x8 w8 = *reinterpret_cast<const u16x8*>(Wpack + (size_t)(chunk * 64 + n) * 256 + kc * 8);
      int idx = n * 256 + ((kc * 8) ^ ((n & 7) << 3));
      *reinterpret_cast<u16x8*>(&Wb[idx]) = w8;
    }
    __syncthreads();

    f32x4 acc[4];
#pragma unroll
    for (int mf = 0; mf < 4; ++mf) acc[mf] = (f32x4){0.f, 0.f, 0.f, 0.f};

#pragma unroll
    for (int s = 0; s < 8; ++s) {
      int k0 = s * 32 + kg * 8;
      int nr = ncol + ln15;
      s16x8 bfr = *reinterpret_cast<const s16x8*>(&Wb[nr * 256 + (k0 ^ ((nr & 7) << 3))]);
#pragma unroll
      for (int mf = 0; mf < 4; ++mf) {
        int m = mf * 16 + ln15;
        s16x8 afr = *reinterpret_cast<const s16x8*>(&Va[m * 256 + (k0 ^ ((m & 7) << 3))]);
        acc[mf] = __builtin_amdgcn_mfma_f32_16x16x32_bf16(afr, bfr, acc[mf], 0, 0, 0);
      }
    }

    // epilogue: C/D map col = lane&15, row = (lane>>4)*4 + reg  [verified m89/m91]
    if (chunk < 4) {
      const float* bias = (chunk == 0) ? b_agn : (chunk == 1) ? b_nga : (chunk == 2) ? b_qna : b_qan;
      int c = ncol + ln15;
      float bv = bias[c];
      if (chunk == 1) {
#pragma unroll
        for (int mf = 0; mf < 4; ++mf)
#pragma unroll
          for (int r = 0; r < 4; ++r) {
            int m = mf * 16 + kg * 4 + r;
            nga[(size_t)(row0 + m) * 64 + c] = acc[mf][r] + bv;
          }
      } else {
        u16* dst = (chunk == 0) ? agn : (chunk == 2) ? qna : qan;
#pragma unroll
        for (int mf = 0; mf < 4; ++mf)
#pragma unroll
          for (int r = 0; r < 4; ++r) {
            int m = mf * 16 + kg * 4 + r;
            dst[(size_t)(row0 + m) * 64 + c] = f2bf(acc[mf][r] + bv);
          }
      }
    } else {
      // only global col 256 (wave 0, ln15==0) is real: node logits
      if (wave == 0 && ln15 == 0) {
#pragma unroll
        for (int mf = 0; mf < 4; ++mf)
#pragma unroll
          for (int r = 0; r < 4; ++r) {
            int m = mf * 16 + kg * 4 + r;
            nl[row0 + m] = acc[mf][r];
          }
      }
    }
  }
}

// ---------- K2: one block per segment ----------
__global__ __launch_bounds__(1024) void k2_segment(
    const u16* __restrict__ agn, const float* __restrict__ nga,
    const u16* __restrict__ qna, const u16* __restrict__ qan,
    const float* __restrict__ nl, const int* __restrict__ seg_start,
    const void* __restrict__ mask, const int* __restrict__ mkind,
    float* __restrict__ p_a, float* __restrict__ entropy, float* __restrict__ value,
    float* __restrict__ Mu, float* __restrict__ Su) {
  const int g = blockIdx.x;
  const int s = seg_start[g], e = seg_start[g + 1];
  const int n = e - s;
  const int t = threadIdx.x, lane = t & 63, wave = t >> 6;
  const int kind = mkind[0];

  __shared__ float wbuf[16];
  __shared__ float cm[16][64], cs[16][64], cv[16][64], ci[16][64], cp[16][64], cq[16][64];

  // phase A: node-logit softmax stats
  float lmax = -3e38f;
  for (int i = s + t; i < e; i += 1024) lmax = fmaxf(lmax, nl[i]);
  lmax = wred_max(lmax);
  if (lane == 0) wbuf[wave] = lmax;
  __syncthreads();
  float Mn = -3e38f;
#pragma unroll
  for (int w = 0; w < 16; ++w) Mn = fmaxf(Mn, wbuf[w]);
  __syncthreads();
  float lsum = 0.f;
  for (int i = s + t; i < e; i += 1024) lsum += expf(nl[i] - Mn);
  lsum = wred_sum(lsum);
  if (lane == 0) wbuf[wave] = lsum;
  __syncthreads();
  float Sn = 0.f;
#pragma unroll
  for (int w = 0; w < 16; ++w) Sn += wbuf[w];
  float invSn = (Sn > 0.f) ? 1.f / Sn : 0.f;

  // phase B: wave-per-node stream. lane = action.
  const bool mv = mask_at(mask, kind, g * 64 + lane);
  float m_u = -3e38f, s_u = 0.f, v_u = 0.f, i_u = 0.f, pa = 0.f, qa = 0.f;
  for (int i = s + wave; i < e; i += 16) {
    size_t base = (size_t)i * 64 + lane;
    float pn = expf(nl[i] - Mn) * invSn;
    // p(a|n): masked row softmax over actions
    float x = mv ? bf2f(agn[base]) : NEG_V;
    float rm = wred_max(x);
    float ev = expf(x - rm);
    float rs = wred_sum(ev);
    pa += pn * (ev / rs);
    // online segment softmax over nga (unmasked == masked stats when valid)
    float y = nga[base];
    if (y > m_u) {
      float sc = expf(m_u - y);
      s_u *= sc; v_u *= sc; i_u *= sc; m_u = y;
    }
    float ee = expf(y - m_u);
    s_u += ee;
    v_u += ee * y;
    i_u += ee * bf2f(qna[base]);
    qa += bf2f(qan[base]);
  }
  cm[wave][lane] = m_u; cs[wave][lane] = s_u; cv[wave][lane] = v_u;
  ci[wave][lane] = i_u; cp[wave][lane] = pa;  cq[wave][lane] = qa;
  __syncthreads();

  if (t < 64) {
    int a = t;
    float M = -3e38f;
#pragma unroll
    for (int w = 0; w < 16; ++w) M = fmaxf(M, cm[w][a]);
    float S = 0.f, V = 0.f, I = 0.f, P = 0.f, Q = 0.f;
#pragma unroll
    for (int w = 0; w < 16; ++w) {
      float sc = expf(cm[w][a] - M);
      S += cs[w][a] * sc; V += cv[w][a] * sc; I += ci[w][a] * sc;
      P += cp[w][a]; Q += cq[w][a];
    }
    p_a[g * 64 + a] = P;
    Mu[g * 64 + a] = M;
    Su[g * 64 + a] = S;
    float inner = (S > 0.f) ? I / S : 0.f;
    bool mva = mask_at(mask, kind, g * 64 + a);
    float Hn;
    if (n <= 0) Hn = 0.f;
    else if (!mva) Hn = -logf(1.0f / (float)n + EPS_V);      // uniform over segment
    else Hn = (S > 0.f) ? (M + logf(S) - V / S) : 0.f;
    float ent_c = -P * logf(P + EPS_V) + P * Hn;
    float val_c = P * (Q + inner);
    ent_c = wred_sum(ent_c);
    val_c = wred_sum(val_c);
    if (a == 0) { entropy[g] = ent_c; value[g] = val_c; }
  }
}

// ---------- K3: logprob (reads nga logits still in d_out region) ----------
__global__ __launch_bounds__(256) void k3_logprob(
    const float* __restrict__ p_a, const float* __restrict__ ngal,
    const int* __restrict__ indices, const int* __restrict__ a_action,
    const int* __restrict__ a_node, const void* __restrict__ mask,
    const int* __restrict__ mkind, const int* __restrict__ n_nodes,
    const float* __restrict__ Mu, const float* __restrict__ Su,
    float* __restrict__ logprob, int G) {
  int g = blockIdx.x * blockDim.x + threadIdx.x;
  if (g >= G) return;
  int kind = mkind[0];
  int a = a_action[g];
  float t1 = logf(p_a[g * 64 + a] + EPS_V);
  int node = a_node[g];
  int g2 = indices[node];
  float p2;
  if (mask_at(mask, kind, g2 * 64 + a)) {
    float S = Su[g2 * 64 + a];
    p2 = (S > 0.f) ? expf(ngal[(size_t)node * 64 + a] - Mu[g2 * 64 + a]) / S : 0.f;
  } else {
    p2 = 1.0f / (float)n_nodes[g2];
  }
  logprob[g] = t1 + logf(p2 + EPS_V);
}

// ---------- K4: in-place p_n__a = exp(x - Mu)/Su ----------
__global__ __launch_bounds__(256) void k4_pna(
    float* __restrict__ pna, const int* __restrict__ indices,
    const float* __restrict__ Mu, const float* __restrict__ Su, int total) {
  int stride = gridDim.x * blockDim.x;
  for (int e = blockIdx.x * blockDim.x + threadIdx.x; e < total; e += stride) {
    int i = e >> 6, a = e & 63;
    int g = indices[i];
    float S = Su[g * 64 + a];
    float x = pna[e];
    pna[e] = (S > 0.f) ? expf(x - Mu[g * 64 + a]) / S : 0.f;
  }
}

extern "C" void kernel_launch(void* const* d_in, const int* in_sizes, int n_in,
                              void* d_out, int out_size, void* d_ws, size_t ws_size,
                              hipStream_t stream) {
  const float* values = (const float*)d_in[0];
  const int* indices = (const int*)d_in[1];
  const int* a_action = (const int*)d_in[2];
  const int* a_node = (const int*)d_in[3];
  const void* action_mask = d_in[4];
  const int* n_nodes = (const int*)d_in[5];
  const float* w_node = (const float*)d_in[6];
  const float* W_agn = (const float*)d_in[7];
  const float* b_agn = (const float*)d_in[8];
  const float* W_nga = (const float*)d_in[9];
  const float* b_nga = (const float*)d_in[10];
  const float* W_qna = (const float*)d_in[11];
  const float* b_qna = (const float*)d_in[12];
  const float* W_qan = (const float*)d_in[13];
  const float* b_qan = (const float*)d_in[14];

  const int N = in_sizes[1];   // 131072
  const int G = in_sizes[2];   // 256
  const int A = 64;
  const int GA = in_sizes[4];  // G*A

  float* out = (float*)d_out;
  float* o_logprob = out;
  float* o_entropy = out + G;
  float* o_value = out + 2 * G;
  float* o_pa = out + 3 * G;
  float* o_pna = out + 3 * G + G * A;   // also holds nga logits between K1 and K4

  char* w = (char*)d_ws;
  size_t off = 0;
  u16* agn = (u16*)(w + off); off += (size_t)N * A * 2;
  u16* qna = (u16*)(w + off); off += (size_t)N * A * 2;
  u16* qan = (u16*)(w + off); off += (size_t)N * A * 2;
  float* nl = (float*)(w + off); off += (size_t)N * 4;
  float* Mu = (float*)(w + off); off += (size_t)G * A * 4;
  float* Su = (float*)(w + off); off += (size_t)G * A * 4;
  int* seg_start = (int*)(w + off); off += (size_t)(G + 1) * 4;
  int* mkind = (int*)(w + off); off += 256;
  off = (off + 255) & ~(size_t)255;
  u16* Wpack = (u16*)(w + off); off += (size_t)320 * 256 * 2;

  k0_scan<<<1, 64, 0, stream>>>(n_nodes, seg_start, G);
  k0_detect<<<1, 256, 0, stream>>>((const unsigned int*)action_mask, GA / 4, mkind);
  k0_pack<<<320, 256, 0, stream>>>(w_node, W_agn, W_nga, W_qna, W_qan, Wpack);
  k1_gemm<<<N / 64, 256, 0, stream>>>(values, Wpack, b_agn, b_nga, b_qna, b_qan,
                                      agn, o_pna, qna, qan, nl);
  k2_segment<<<G, 1024, 0, stream>>>(agn, o_pna, qna, qan, nl, seg_start,
                                     action_mask, mkind, o_pa, o_entropy, o_value, Mu, Su);
  k3_logprob<<<1, 256, 0, stream>>>(o_pa, o_pna, indices, a_action, a_node,
                                    action_mask, mkind, n_nodes, Mu, Su, o_logprob, G);
  k4_pna<<<2048, 256, 0, stream>>>(o_pna, indices, Mu, Su, N * A);
}

// Round 3
// 145.510 us; speedup vs baseline: 1.0369x; 1.0369x over previous
//
#include <hip/hip_runtime.h>
#include <hip/hip_bf16.h>

typedef unsigned short u16;
typedef __attribute__((ext_vector_type(4))) float f32x4;
typedef __attribute__((ext_vector_type(8))) short s16x8;
typedef __attribute__((ext_vector_type(8))) unsigned short u16x8;

#define EPS_V (1e-10f)

__device__ __forceinline__ u16 f2bf(float f) {
  unsigned u = __float_as_uint(f);
  u += 0x7fffu + ((u >> 16) & 1u);
  return (u16)(u >> 16);
}
__device__ __forceinline__ float bf2f(u16 h) {
  return __uint_as_float(((unsigned)h) << 16);
}
__device__ __forceinline__ float wred_sum(float v) {
#pragma unroll
  for (int o = 32; o; o >>= 1) v += __shfl_xor(v, o);
  return v;
}
// mask accessor robust to int32 / float32 / byte storage of the bool mask
__device__ __forceinline__ bool mask_at(const void* m, int kind, int idx) {
  if (kind == 0) return ((const int*)m)[idx] != 0;
  if (kind == 1) return ((const float*)m)[idx] != 0.0f;
  return ((const unsigned char*)m)[idx] != 0;
}

// ---------- K0a: exclusive scan of n_nodes -> seg_start[G+1] ----------
__global__ void k0_scan(const int* __restrict__ n_nodes, int* __restrict__ seg_start, int G) {
  if (blockIdx.x == 0 && threadIdx.x == 0) {
    int acc = 0;
    for (int g = 0; g < G; ++g) { seg_start[g] = acc; acc += n_nodes[g]; }
    seg_start[G] = acc;
  }
}

// ---------- K0c: detect action_mask storage dtype ----------
__global__ __launch_bounds__(256) void k0_detect(const unsigned int* __restrict__ m,
                                                 int ndw, int* __restrict__ kind) {
  __shared__ int notInt, notFloat;
  if (threadIdx.x == 0) { notInt = 0; notFloat = 0; }
  __syncthreads();
  int li = 0, lf = 0;
  for (int i = threadIdx.x; i < ndw; i += 256) {
    unsigned v = m[i];
    if (v != 0u && v != 1u) li = 1;
    if (v != 0u && v != 0x3F800000u) lf = 1;
  }
  if (li) atomicOr(&notInt, 1);
  if (lf) atomicOr(&notFloat, 1);
  __syncthreads();
  if (threadIdx.x == 0) kind[0] = (!notInt) ? 0 : ((!notFloat) ? 1 : 2);
}

// ---------- K0b: pack weights to bf16 [320 cols][256 k] ----------
__global__ __launch_bounds__(256) void k0_pack(
    const float* __restrict__ w_node, const float* __restrict__ W_agn,
    const float* __restrict__ W_nga, const float* __restrict__ W_qna,
    const float* __restrict__ W_qan, u16* __restrict__ Wpack) {
  int idx = blockIdx.x * 256 + threadIdx.x;  // < 320*256
  int col = idx >> 8, k = idx & 255;
  float v = 0.f;
  if (col < 64) v = W_agn[col * 256 + k];
  else if (col < 128) v = W_nga[(col - 64) * 256 + k];
  else if (col < 192) v = W_qna[(col - 128) * 256 + k];
  else if (col < 256) v = W_qan[(col - 192) * 256 + k];
  else if (col == 256) v = w_node[k];
  Wpack[idx] = f2bf(v);
}

// ---------- K1: bf16 MFMA GEMM. A staged in LDS once; B direct from L2 to regs.
// One barrier per block. Outputs bf16 (nga optionally f32 -> nga_f32 when no ws room).
__global__ __launch_bounds__(256) void k1_gemm(
    const float* __restrict__ values, const u16* __restrict__ Wpack,
    const float* __restrict__ b_agn, const float* __restrict__ b_nga,
    const float* __restrict__ b_qna, const float* __restrict__ b_qan,
    u16* __restrict__ agn, u16* __restrict__ nga_bf, float* __restrict__ nga_f32,
    u16* __restrict__ qna, u16* __restrict__ qan,
    float* __restrict__ nl, int nga_is_bf) {
  __shared__ u16 Va[64 * 256];  // XOR-swizzled: elem = m*256 + (k ^ ((m&7)<<3))
  const int t = threadIdx.x;
  const int row0 = blockIdx.x * 64;

  // stage values tile (fp32 -> bf16), swizzled. wave-instr = 1 row, 64 float4s.
#pragma unroll
  for (int it = 0; it < 16; ++it) {
    int flat = t + 256 * it;
    int m = flat >> 6, fc = flat & 63;
    const float4 v = reinterpret_cast<const float4*>(values + (size_t)(row0 + m) * 256)[fc];
    ushort4 h;
    h.x = f2bf(v.x); h.y = f2bf(v.y); h.z = f2bf(v.z); h.w = f2bf(v.w);
    int idx = m * 256 + ((fc * 4) ^ ((m & 7) << 3));
    *reinterpret_cast<ushort4*>(&Va[idx]) = h;
  }
  __syncthreads();   // the only barrier

  const int lane = t & 63;
  const int wave = t >> 6;
  const int ln15 = lane & 15;
  const int kg = lane >> 4;
  const int ncol = wave * 16;

  for (int chunk = 0; chunk < 5; ++chunk) {
    if (chunk == 4 && wave != 0) break;   // only col 256 (w_node) is real
    const int cl = ncol + ln15;                 // local col in chunk
    const size_t gc = (size_t)(chunk * 64 + cl) * 256;
    // B fragments straight from L2 (no LDS): lanes {l,l+16,l+32,l+48} = one 64B line
    s16x8 bfr[8];
#pragma unroll
    for (int s = 0; s < 8; ++s)
      bfr[s] = *reinterpret_cast<const s16x8*>(Wpack + gc + s * 32 + kg * 8);

    f32x4 acc[4];
#pragma unroll
    for (int mf = 0; mf < 4; ++mf) acc[mf] = (f32x4){0.f, 0.f, 0.f, 0.f};

#pragma unroll
    for (int s = 0; s < 8; ++s) {
      int k0 = s * 32 + kg * 8;
#pragma unroll
      for (int mf = 0; mf < 4; ++mf) {
        int m = mf * 16 + ln15;
        s16x8 afr = *reinterpret_cast<const s16x8*>(&Va[m * 256 + (k0 ^ ((m & 7) << 3))]);
        acc[mf] = __builtin_amdgcn_mfma_f32_16x16x32_bf16(afr, bfr[s], acc[mf], 0, 0, 0);
      }
    }

    // epilogue: C/D map col = lane&15, row = (lane>>4)*4 + reg  [m89/m91]
    if (chunk < 4) {
      const float* bias = (chunk == 0) ? b_agn : (chunk == 1) ? b_nga
                        : (chunk == 2) ? b_qna : b_qan;
      float bv = bias[cl];
      if (chunk == 1 && !nga_is_bf) {
#pragma unroll
        for (int mf = 0; mf < 4; ++mf)
#pragma unroll
          for (int r = 0; r < 4; ++r) {
            int m = mf * 16 + kg * 4 + r;
            nga_f32[(size_t)(row0 + m) * 64 + cl] = acc[mf][r] + bv;
          }
      } else {
        u16* dst = (chunk == 0) ? agn : (chunk == 1) ? nga_bf
                 : (chunk == 2) ? qna : qan;
#pragma unroll
        for (int mf = 0; mf < 4; ++mf)
#pragma unroll
          for (int r = 0; r < 4; ++r) {
            int m = mf * 16 + kg * 4 + r;
            dst[(size_t)(row0 + m) * 64 + cl] = f2bf(acc[mf][r] + bv);
          }
      }
    } else if (ln15 == 0) {   // wave 0, node-logit column
#pragma unroll
      for (int mf = 0; mf < 4; ++mf)
#pragma unroll
        for (int r = 0; r < 4; ++r)
          nl[row0 + mf * 16 + kg * 4 + r] = acc[mf][r];
    }
  }
}

// ---------- K2: one block per segment. No-max softmax (logits bounded ~±2). ----------
__global__ __launch_bounds__(1024) void k2_segment(
    const u16* __restrict__ agn, const u16* __restrict__ nga_bf,
    const float* __restrict__ nga_f32, const u16* __restrict__ qna,
    const u16* __restrict__ qan, const float* __restrict__ nl,
    const int* __restrict__ seg_start, const void* __restrict__ mask,
    const int* __restrict__ mkind,
    float* __restrict__ p_a, float* __restrict__ entropy, float* __restrict__ value,
    float* __restrict__ Su, int nga_is_bf) {
  const int g = blockIdx.x;
  const int s = seg_start[g], e = seg_start[g + 1];
  const int n = e - s;
  const int t = threadIdx.x, lane = t & 63, wave = t >> 4 >> 2;  // wave = t>>6

  __shared__ float wbuf[16];
  __shared__ float cs[16][64], cv[16][64], ci[16][64], cp[16][64], cq[16][64];

  // phase A: Sn = sum exp(nl) over segment (no max needed)
  float ls = 0.f;
  for (int i = s + t; i < e; i += 1024) ls += __expf(nl[i]);
  ls = wred_sum(ls);
  if (lane == 0) wbuf[wave] = ls;
  __syncthreads();
  float Sn = 0.f;
#pragma unroll
  for (int w = 0; w < 16; ++w) Sn += wbuf[w];
  float invSn = (Sn > 0.f) ? 1.f / Sn : 0.f;

  // phase B: wave-per-node stream. lane = action.
  const int kind = mkind[0];
  const bool mv = mask_at(mask, kind, g * 64 + lane);
  float s_u = 0.f, v_u = 0.f, i_u = 0.f, pa = 0.f, qa = 0.f;
  for (int i = s + wave; i < e; i += 16) {
    size_t base = (size_t)i * 64 + lane;
    float pn = __expf(nl[i]) * invSn;
    // p(a|n): masked row softmax, no max
    float ev = mv ? __expf(bf2f(agn[base])) : 0.f;
    float rs = wred_sum(ev);
    pa += pn * ((rs > 0.f) ? ev / rs : 0.015625f);  // all-masked row -> uniform 1/64
    // unmasked segment stats over nga
    float y = nga_is_bf ? bf2f(nga_bf[base]) : nga_f32[base];
    float ey = __expf(y);
    s_u += ey;
    v_u += ey * y;
    i_u += ey * bf2f(qna[base]);
    qa += bf2f(qan[base]);
  }
  cs[wave][lane] = s_u; cv[wave][lane] = v_u; ci[wave][lane] = i_u;
  cp[wave][lane] = pa;  cq[wave][lane] = qa;
  __syncthreads();

  if (t < 64) {
    int a = t;
    float S = 0.f, V = 0.f, I = 0.f, P = 0.f, Q = 0.f;
#pragma unroll
    for (int w = 0; w < 16; ++w) {
      S += cs[w][a]; V += cv[w][a]; I += ci[w][a]; P += cp[w][a]; Q += cq[w][a];
    }
    p_a[g * 64 + a] = P;
    Su[g * 64 + a] = S;
    float inner = (S > 0.f) ? I / S : 0.f;
    bool mva = mask_at(mask, kind, g * 64 + a);
    float Hn;
    if (n <= 0) Hn = 0.f;
    else if (!mva) Hn = -logf(1.0f / (float)n + EPS_V);   // uniform over segment
    else Hn = (S > 0.f) ? (logf(S) - V / S) : 0.f;
    float ent_c = -P * logf(P + EPS_V) + P * Hn;
    float val_c = P * (Q + inner);
    ent_c = wred_sum(ent_c);
    val_c = wred_sum(val_c);
    if (a == 0) { entropy[g] = ent_c; value[g] = val_c; }
  }
}

// ---------- K3: logprob ----------
__global__ __launch_bounds__(256) void k3_logprob(
    const float* __restrict__ p_a, const u16* __restrict__ nga_bf,
    const float* __restrict__ nga_f32, const int* __restrict__ indices,
    const int* __restrict__ a_action, const int* __restrict__ a_node,
    const void* __restrict__ mask, const int* __restrict__ mkind,
    const int* __restrict__ n_nodes, const float* __restrict__ Su,
    float* __restrict__ logprob, int G, int nga_is_bf) {
  int g = blockIdx.x * blockDim.x + threadIdx.x;
  if (g >= G) return;
  int kind = mkind[0];
  int a = a_action[g];
  float t1 = logf(p_a[g * 64 + a] + EPS_V);
  int node = a_node[g];
  int g2 = indices[node];
  float p2;
  if (mask_at(mask, kind, g2 * 64 + a)) {
    float S = Su[g2 * 64 + a];
    float y = nga_is_bf ? bf2f(nga_bf[(size_t)node * 64 + a]) : nga_f32[(size_t)node * 64 + a];
    p2 = (S > 0.f) ? __expf(y) / S : 0.f;
  } else {
    p2 = 1.0f / (float)n_nodes[g2];
  }
  logprob[g] = t1 + logf(p2 + EPS_V);
}

// ---------- K4 (bf16 path): p_n__a = exp(y)/Su, 8 elems/thread ----------
__global__ __launch_bounds__(256) void k4_pna_bf(
    const u16* __restrict__ nga_bf, const int* __restrict__ indices,
    const float* __restrict__ Su, float* __restrict__ pna, int N) {
  int e8 = blockIdx.x * 256 + threadIdx.x;
  if (e8 >= N * 8) return;
  int i = e8 >> 3, a0 = (e8 & 7) * 8;
  int g = indices[i];
  u16x8 y = *reinterpret_cast<const u16x8*>(nga_bf + (size_t)i * 64 + a0);
  float4 S0 = *reinterpret_cast<const float4*>(Su + g * 64 + a0);
  float4 S1 = *reinterpret_cast<const float4*>(Su + g * 64 + a0 + 4);
  float4 o0, o1;
  o0.x = __expf(bf2f(y[0])) / S0.x; o0.y = __expf(bf2f(y[1])) / S0.y;
  o0.z = __expf(bf2f(y[2])) / S0.z; o0.w = __expf(bf2f(y[3])) / S0.w;
  o1.x = __expf(bf2f(y[4])) / S1.x; o1.y = __expf(bf2f(y[5])) / S1.y;
  o1.z = __expf(bf2f(y[6])) / S1.z; o1.w = __expf(bf2f(y[7])) / S1.w;
  float4* dst = reinterpret_cast<float4*>(pna + (size_t)i * 64 + a0);
  dst[0] = o0; dst[1] = o1;
}

// ---------- K4 (f32 fallback, in-place): p = exp(x)/Su ----------
__global__ __launch_bounds__(256) void k4_pna_f32(
    float* __restrict__ pna, const int* __restrict__ indices,
    const float* __restrict__ Su, int N) {
  int e4 = blockIdx.x * 256 + threadIdx.x;
  if (e4 >= N * 16) return;
  int i = e4 >> 4, a0 = (e4 & 15) * 4;
  int g = indices[i];
  float4* p = reinterpret_cast<float4*>(pna + (size_t)i * 64 + a0);
  float4 x = *p;
  float4 S = *reinterpret_cast<const float4*>(Su + g * 64 + a0);
  float4 o;
  o.x = __expf(x.x) / S.x; o.y = __expf(x.y) / S.y;
  o.z = __expf(x.z) / S.z; o.w = __expf(x.w) / S.w;
  *p = o;
}

extern "C" void kernel_launch(void* const* d_in, const int* in_sizes, int n_in,
                              void* d_out, int out_size, void* d_ws, size_t ws_size,
                              hipStream_t stream) {
  const float* values = (const float*)d_in[0];
  const int* indices = (const int*)d_in[1];
  const int* a_action = (const int*)d_in[2];
  const int* a_node = (const int*)d_in[3];
  const void* action_mask = d_in[4];
  const int* n_nodes = (const int*)d_in[5];
  const float* w_node = (const float*)d_in[6];
  const float* W_agn = (const float*)d_in[7];
  const float* b_agn = (const float*)d_in[8];
  const float* W_nga = (const float*)d_in[9];
  const float* b_nga = (const float*)d_in[10];
  const float* W_qna = (const float*)d_in[11];
  const float* b_qna = (const float*)d_in[12];
  const float* W_qan = (const float*)d_in[13];
  const float* b_qan = (const float*)d_in[14];

  const int N = in_sizes[1];   // 131072
  const int G = in_sizes[2];   // 256
  const int A = 64;
  const int GA = in_sizes[4];  // G*A

  float* out = (float*)d_out;
  float* o_logprob = out;
  float* o_entropy = out + G;
  float* o_value = out + 2 * G;
  float* o_pa = out + 3 * G;
  float* o_pna = out + 3 * G + G * A;

  char* w = (char*)d_ws;
  size_t off = 0;
  u16* agn = (u16*)(w + off); off += (size_t)N * A * 2;
  u16* qna = (u16*)(w + off); off += (size_t)N * A * 2;
  u16* qan = (u16*)(w + off); off += (size_t)N * A * 2;
  float* nl = (float*)(w + off); off += (size_t)N * 4;
  float* Su = (float*)(w + off); off += (size_t)G * A * 4;
  int* seg_start = (int*)(w + off); off += (size_t)(G + 1) * 4;
  int* mkind = (int*)(w + off); off += 256;
  off = (off + 255) & ~(size_t)255;
  u16* Wpack = (u16*)(w + off); off += (size_t)320 * 256 * 2;
  // nga bf16 goes last so the base layout is path-independent
  u16* nga_bf = (u16*)(w + off);
  size_t need_bf = off + (size_t)N * A * 2;
  int nga_is_bf = (ws_size >= need_bf) ? 1 : 0;
  float* nga_f32 = o_pna;   // fallback: f32 logits staged in d_out, K4 in-place

  k0_scan<<<1, 64, 0, stream>>>(n_nodes, seg_start, G);
  k0_detect<<<1, 256, 0, stream>>>((const unsigned int*)action_mask, GA / 4, mkind);
  k0_pack<<<320, 256, 0, stream>>>(w_node, W_agn, W_nga, W_qna, W_qan, Wpack);
  k1_gemm<<<N / 64, 256, 0, stream>>>(values, Wpack, b_agn, b_nga, b_qna, b_qan,
                                      agn, nga_bf, nga_f32, qna, qan, nl, nga_is_bf);
  k2_segment<<<G, 1024, 0, stream>>>(agn, nga_bf, nga_f32, qna, qan, nl, seg_start,
                                     action_mask, mkind, o_pa, o_entropy, o_value,
                                     Su, nga_is_bf);
  k3_logprob<<<1, 256, 0, stream>>>(o_pa, nga_bf, nga_f32, indices, a_action, a_node,
                                    action_mask, mkind, n_nodes, Su, o_logprob, G,
                                    nga_is_bf);
  if (nga_is_bf)
    k4_pna_bf<<<(N * 8 + 255) / 256, 256, 0, stream>>>(nga_bf, indices, Su, o_pna, N);
  else
    k4_pna_f32<<<(N * 16 + 255) / 256, 256, 0, stream>>>(o_pna, indices, Su, N);
}

// Round 4
// 139.877 us; speedup vs baseline: 1.0786x; 1.0403x over previous
//
#include <hip/hip_runtime.h>
#include <hip/hip_bf16.h>

typedef unsigned short u16;
typedef __attribute__((ext_vector_type(4))) float f32x4;
typedef __attribute__((ext_vector_type(8))) short s16x8;
typedef __attribute__((ext_vector_type(8))) unsigned short u16x8;

#define EPS_V (1e-10f)

__device__ __forceinline__ u16 f2bf(float f) {
  unsigned u = __float_as_uint(f);
  u += 0x7fffu + ((u >> 16) & 1u);
  return (u16)(u >> 16);
}
__device__ __forceinline__ float bf2f(u16 h) {
  return __uint_as_float(((unsigned)h) << 16);
}
__device__ __forceinline__ float wred_sum(float v) {
#pragma unroll
  for (int o = 32; o; o >>= 1) v += __shfl_xor(v, o);
  return v;
}
// mask accessor robust to int32 / float32 / byte storage of the bool mask
__device__ __forceinline__ bool mask_at(const void* m, int kind, int idx) {
  if (kind == 0) return ((const int*)m)[idx] != 0;
  if (kind == 1) return ((const float*)m)[idx] != 0.0f;
  return ((const unsigned char*)m)[idx] != 0;
}

// ---------- K0a: exclusive scan of n_nodes -> seg_start[G+1] ----------
__global__ void k0_scan(const int* __restrict__ n_nodes, int* __restrict__ seg_start, int G) {
  if (blockIdx.x == 0 && threadIdx.x == 0) {
    int acc = 0;
    for (int g = 0; g < G; ++g) { seg_start[g] = acc; acc += n_nodes[g]; }
    seg_start[G] = acc;
  }
}

// ---------- K0c: detect action_mask storage dtype ----------
__global__ __launch_bounds__(256) void k0_detect(const unsigned int* __restrict__ m,
                                                 int ndw, int* __restrict__ kind) {
  __shared__ int notInt, notFloat;
  if (threadIdx.x == 0) { notInt = 0; notFloat = 0; }
  __syncthreads();
  int li = 0, lf = 0;
  for (int i = threadIdx.x; i < ndw; i += 256) {
    unsigned v = m[i];
    if (v != 0u && v != 1u) li = 1;
    if (v != 0u && v != 0x3F800000u) lf = 1;
  }
  if (li) atomicOr(&notInt, 1);
  if (lf) atomicOr(&notFloat, 1);
  __syncthreads();
  if (threadIdx.x == 0) kind[0] = (!notInt) ? 0 : ((!notFloat) ? 1 : 2);
}

// ---------- K0b: pack weights to bf16 [320 cols][256 k] ----------
__global__ __launch_bounds__(256) void k0_pack(
    const float* __restrict__ w_node, const float* __restrict__ W_agn,
    const float* __restrict__ W_nga, const float* __restrict__ W_qna,
    const float* __restrict__ W_qan, u16* __restrict__ Wpack) {
  int idx = blockIdx.x * 256 + threadIdx.x;  // < 320*256
  int col = idx >> 8, k = idx & 255;
  float v = 0.f;
  if (col < 64) v = W_agn[col * 256 + k];
  else if (col < 128) v = W_nga[(col - 64) * 256 + k];
  else if (col < 192) v = W_qna[(col - 128) * 256 + k];
  else if (col < 256) v = W_qan[(col - 192) * 256 + k];
  else if (col == 256) v = w_node[k];
  Wpack[idx] = f2bf(v);
}

// ---------- K1: bf16 MFMA GEMM, k-slice outer, all 4 chunks accumulated.
// A staged once in LDS (read 1x per slice); B direct from L2. 1 barrier.
__global__ __launch_bounds__(256, 4) void k1_gemm(
    const float* __restrict__ values, const u16* __restrict__ Wpack,
    const float* __restrict__ b_agn, const float* __restrict__ b_nga,
    const float* __restrict__ b_qna, const float* __restrict__ b_qan,
    u16* __restrict__ agn, u16* __restrict__ nga_bf, float* __restrict__ nga_f32,
    u16* __restrict__ qna, u16* __restrict__ qan,
    float* __restrict__ nl, int nga_is_bf) {
  __shared__ u16 Va[64 * 256];  // XOR-swizzled: elem = m*256 + (k ^ ((m&7)<<3))
  const int t = threadIdx.x;
  const int row0 = blockIdx.x * 64;

  // stage values tile (fp32 -> bf16), swizzled
#pragma unroll
  for (int it = 0; it < 16; ++it) {
    int flat = t + 256 * it;
    int m = flat >> 6, fc = flat & 63;
    const float4 v = reinterpret_cast<const float4*>(values + (size_t)(row0 + m) * 256)[fc];
    ushort4 h;
    h.x = f2bf(v.x); h.y = f2bf(v.y); h.z = f2bf(v.z); h.w = f2bf(v.w);
    int idx = m * 256 + ((fc * 4) ^ ((m & 7) << 3));
    *reinterpret_cast<ushort4*>(&Va[idx]) = h;
  }
  __syncthreads();   // the only barrier

  const int lane = t & 63;
  const int wave = t >> 6;
  const int ln15 = lane & 15;
  const int kg = lane >> 4;
  const int ncol = wave * 16;
  const int sw = (ln15 & 7) << 3;          // swizzle shift (row-uniform per lane)

  // per-lane B base: col = chunk*64 + ncol + ln15, k offset kg*8
  const u16* wbase = Wpack + (size_t)(ncol + ln15) * 256 + kg * 8;

  f32x4 acc[4][4];
#pragma unroll
  for (int c = 0; c < 4; ++c)
#pragma unroll
    for (int mf = 0; mf < 4; ++mf) acc[c][mf] = (f32x4){0.f, 0.f, 0.f, 0.f};

#pragma unroll 4
  for (int s = 0; s < 8; ++s) {
    const int k0 = s * 32 + kg * 8;
    s16x8 a[4];
#pragma unroll
    for (int mf = 0; mf < 4; ++mf) {
      int m = mf * 16 + ln15;
      a[mf] = *reinterpret_cast<const s16x8*>(&Va[m * 256 + (k0 ^ sw)]);
    }
#pragma unroll
    for (int c = 0; c < 4; ++c) {
      s16x8 b = *reinterpret_cast<const s16x8*>(wbase + (size_t)c * 16384 + s * 32);
#pragma unroll
      for (int mf = 0; mf < 4; ++mf)
        acc[c][mf] = __builtin_amdgcn_mfma_f32_16x16x32_bf16(a[mf], b, acc[c][mf], 0, 0, 0);
    }
  }

  // epilogue: C/D map col = lane&15, row = (lane>>4)*4 + reg  [m89/m91]
  const int cl = ncol + ln15;
#pragma unroll
  for (int c = 0; c < 4; ++c) {
    const float* bias = (c == 0) ? b_agn : (c == 1) ? b_nga : (c == 2) ? b_qna : b_qan;
    float bv = bias[cl];
    if (c == 1 && !nga_is_bf) {
#pragma unroll
      for (int mf = 0; mf < 4; ++mf)
#pragma unroll
        for (int r = 0; r < 4; ++r) {
          int m = mf * 16 + kg * 4 + r;
          nga_f32[(size_t)(row0 + m) * 64 + cl] = acc[c][mf][r] + bv;
        }
    } else {
      u16* dst = (c == 0) ? agn : (c == 1) ? nga_bf : (c == 2) ? qna : qan;
#pragma unroll
      for (int mf = 0; mf < 4; ++mf)
#pragma unroll
        for (int r = 0; r < 4; ++r) {
          int m = mf * 16 + kg * 4 + r;
          dst[(size_t)(row0 + m) * 64 + cl] = f2bf(acc[c][mf][r] + bv);
        }
    }
  }

  // node-logit column (global col 256): wave 0 only, post-loop (reuses dead regs)
  if (wave == 0) {
    f32x4 an[4];
#pragma unroll
    for (int mf = 0; mf < 4; ++mf) an[mf] = (f32x4){0.f, 0.f, 0.f, 0.f};
#pragma unroll 4
    for (int s = 0; s < 8; ++s) {
      const int k0 = s * 32 + kg * 8;
      s16x8 b = *reinterpret_cast<const s16x8*>(wbase + (size_t)4 * 16384 + s * 32);
#pragma unroll
      for (int mf = 0; mf < 4; ++mf) {
        int m = mf * 16 + ln15;
        s16x8 a = *reinterpret_cast<const s16x8*>(&Va[m * 256 + (k0 ^ sw)]);
        an[mf] = __builtin_amdgcn_mfma_f32_16x16x32_bf16(a, b, an[mf], 0, 0, 0);
      }
    }
    if (ln15 == 0) {
#pragma unroll
      for (int mf = 0; mf < 4; ++mf)
#pragma unroll
        for (int r = 0; r < 4; ++r)
          nl[row0 + mf * 16 + kg * 4 + r] = an[mf][r];
    }
  }
}

// ---------- K2: one block per segment. No-max softmax (logits bounded ~±2). ----------
__global__ __launch_bounds__(1024) void k2_segment(
    const u16* __restrict__ agn, const u16* __restrict__ nga_bf,
    const float* __restrict__ nga_f32, const u16* __restrict__ qna,
    const u16* __restrict__ qan, const float* __restrict__ nl,
    const int* __restrict__ seg_start, const void* __restrict__ mask,
    const int* __restrict__ mkind,
    float* __restrict__ p_a, float* __restrict__ entropy, float* __restrict__ value,
    float* __restrict__ Su, int nga_is_bf) {
  const int g = blockIdx.x;
  const int s = seg_start[g], e = seg_start[g + 1];
  const int n = e - s;
  const int t = threadIdx.x, lane = t & 63, wave = t >> 6;

  __shared__ float wbuf[16];
  __shared__ float cs[16][64], cv[16][64], ci[16][64], cp[16][64], cq[16][64];

  // phase A: Sn = sum exp(nl) over segment (no max needed)
  float ls = 0.f;
  for (int i = s + t; i < e; i += 1024) ls += __expf(nl[i]);
  ls = wred_sum(ls);
  if (lane == 0) wbuf[wave] = ls;
  __syncthreads();
  float Sn = 0.f;
#pragma unroll
  for (int w = 0; w < 16; ++w) Sn += wbuf[w];
  float invSn = (Sn > 0.f) ? 1.f / Sn : 0.f;

  // phase B: wave-per-node stream. lane = action.
  const int kind = mkind[0];
  const bool mv = mask_at(mask, kind, g * 64 + lane);
  float s_u = 0.f, v_u = 0.f, i_u = 0.f, pa = 0.f, qa = 0.f;
  for (int i = s + wave; i < e; i += 16) {
    size_t base = (size_t)i * 64 + lane;
    float pn = __expf(nl[i]) * invSn;
    // p(a|n): masked row softmax, no max
    float ev = mv ? __expf(bf2f(agn[base])) : 0.f;
    float rs = wred_sum(ev);
    pa += pn * ((rs > 0.f) ? ev / rs : 0.015625f);  // all-masked row -> uniform 1/64
    // unmasked segment stats over nga
    float y = nga_is_bf ? bf2f(nga_bf[base]) : nga_f32[base];
    float ey = __expf(y);
    s_u += ey;
    v_u += ey * y;
    i_u += ey * bf2f(qna[base]);
    qa += bf2f(qan[base]);
  }
  cs[wave][lane] = s_u; cv[wave][lane] = v_u; ci[wave][lane] = i_u;
  cp[wave][lane] = pa;  cq[wave][lane] = qa;
  __syncthreads();

  if (t < 64) {
    int a = t;
    float S = 0.f, V = 0.f, I = 0.f, P = 0.f, Q = 0.f;
#pragma unroll
    for (int w = 0; w < 16; ++w) {
      S += cs[w][a]; V += cv[w][a]; I += ci[w][a]; P += cp[w][a]; Q += cq[w][a];
    }
    p_a[g * 64 + a] = P;
    Su[g * 64 + a] = S;
    float inner = (S > 0.f) ? I / S : 0.f;
    bool mva = mask_at(mask, kind, g * 64 + a);
    float Hn;
    if (n <= 0) Hn = 0.f;
    else if (!mva) Hn = -logf(1.0f / (float)n + EPS_V);   // uniform over segment
    else Hn = (S > 0.f) ? (logf(S) - V / S) : 0.f;
    float ent_c = -P * logf(P + EPS_V) + P * Hn;
    float val_c = P * (Q + inner);
    ent_c = wred_sum(ent_c);
    val_c = wred_sum(val_c);
    if (a == 0) { entropy[g] = ent_c; value[g] = val_c; }
  }
}

// ---------- K3: logprob ----------
__global__ __launch_bounds__(256) void k3_logprob(
    const float* __restrict__ p_a, const u16* __restrict__ nga_bf,
    const float* __restrict__ nga_f32, const int* __restrict__ indices,
    const int* __restrict__ a_action, const int* __restrict__ a_node,
    const void* __restrict__ mask, const int* __restrict__ mkind,
    const int* __restrict__ n_nodes, const float* __restrict__ Su,
    float* __restrict__ logprob, int G, int nga_is_bf) {
  int g = blockIdx.x * blockDim.x + threadIdx.x;
  if (g >= G) return;
  int kind = mkind[0];
  int a = a_action[g];
  float t1 = logf(p_a[g * 64 + a] + EPS_V);
  int node = a_node[g];
  int g2 = indices[node];
  float p2;
  if (mask_at(mask, kind, g2 * 64 + a)) {
    float S = Su[g2 * 64 + a];
    float y = nga_is_bf ? bf2f(nga_bf[(size_t)node * 64 + a]) : nga_f32[(size_t)node * 64 + a];
    p2 = (S > 0.f) ? __expf(y) / S : 0.f;
  } else {
    p2 = 1.0f / (float)n_nodes[g2];
  }
  logprob[g] = t1 + logf(p2 + EPS_V);
}

// ---------- K4 (bf16 path): p_n__a = exp(y)/Su, 8 elems/thread ----------
__global__ __launch_bounds__(256) void k4_pna_bf(
    const u16* __restrict__ nga_bf, const int* __restrict__ indices,
    const float* __restrict__ Su, float* __restrict__ pna, int N) {
  int e8 = blockIdx.x * 256 + threadIdx.x;
  if (e8 >= N * 8) return;
  int i = e8 >> 3, a0 = (e8 & 7) * 8;
  int g = indices[i];
  u16x8 y = *reinterpret_cast<const u16x8*>(nga_bf + (size_t)i * 64 + a0);
  float4 S0 = *reinterpret_cast<const float4*>(Su + g * 64 + a0);
  float4 S1 = *reinterpret_cast<const float4*>(Su + g * 64 + a0 + 4);
  float4 o0, o1;
  o0.x = __expf(bf2f(y[0])) / S0.x; o0.y = __expf(bf2f(y[1])) / S0.y;
  o0.z = __expf(bf2f(y[2])) / S0.z; o0.w = __expf(bf2f(y[3])) / S0.w;
  o1.x = __expf(bf2f(y[4])) / S1.x; o1.y = __expf(bf2f(y[5])) / S1.y;
  o1.z = __expf(bf2f(y[6])) / S1.z; o1.w = __expf(bf2f(y[7])) / S1.w;
  float4* dst = reinterpret_cast<float4*>(pna + (size_t)i * 64 + a0);
  dst[0] = o0; dst[1] = o1;
}

// ---------- K4 (f32 fallback, in-place): p = exp(x)/Su ----------
__global__ __launch_bounds__(256) void k4_pna_f32(
    float* __restrict__ pna, const int* __restrict__ indices,
    const float* __restrict__ Su, int N) {
  int e4 = blockIdx.x * 256 + threadIdx.x;
  if (e4 >= N * 16) return;
  int i = e4 >> 4, a0 = (e4 & 15) * 4;
  int g = indices[i];
  float4* p = reinterpret_cast<float4*>(pna + (size_t)i * 64 + a0);
  float4 x = *p;
  float4 S = *reinterpret_cast<const float4*>(Su + g * 64 + a0);
  float4 o;
  o.x = __expf(x.x) / S.x; o.y = __expf(x.y) / S.y;
  o.z = __expf(x.z) / S.z; o.w = __expf(x.w) / S.w;
  *p = o;
}

extern "C" void kernel_launch(void* const* d_in, const int* in_sizes, int n_in,
                              void* d_out, int out_size, void* d_ws, size_t ws_size,
                              hipStream_t stream) {
  const float* values = (const float*)d_in[0];
  const int* indices = (const int*)d_in[1];
  const int* a_action = (const int*)d_in[2];
  const int* a_node = (const int*)d_in[3];
  const void* action_mask = d_in[4];
  const int* n_nodes = (const int*)d_in[5];
  const float* w_node = (const float*)d_in[6];
  const float* W_agn = (const float*)d_in[7];
  const float* b_agn = (const float*)d_in[8];
  const float* W_nga = (const float*)d_in[9];
  const float* b_nga = (const float*)d_in[10];
  const float* W_qna = (const float*)d_in[11];
  const float* b_qna = (const float*)d_in[12];
  const float* W_qan = (const float*)d_in[13];
  const float* b_qan = (const float*)d_in[14];

  const int N = in_sizes[1];   // 131072
  const int G = in_sizes[2];   // 256
  const int A = 64;
  const int GA = in_sizes[4];  // G*A

  float* out = (float*)d_out;
  float* o_logprob = out;
  float* o_entropy = out + G;
  float* o_value = out + 2 * G;
  float* o_pa = out + 3 * G;
  float* o_pna = out + 3 * G + G * A;

  char* w = (char*)d_ws;
  size_t off = 0;
  u16* agn = (u16*)(w + off); off += (size_t)N * A * 2;
  u16* qna = (u16*)(w + off); off += (size_t)N * A * 2;
  u16* qan = (u16*)(w + off); off += (size_t)N * A * 2;
  float* nl = (float*)(w + off); off += (size_t)N * 4;
  float* Su = (float*)(w + off); off += (size_t)G * A * 4;
  int* seg_start = (int*)(w + off); off += (size_t)(G + 1) * 4;
  int* mkind = (int*)(w + off); off += 256;
  off = (off + 255) & ~(size_t)255;
  u16* Wpack = (u16*)(w + off); off += (size_t)320 * 256 * 2;
  // nga bf16 goes last so the base layout is path-independent
  u16* nga_bf = (u16*)(w + off);
  size_t need_bf = off + (size_t)N * A * 2;
  int nga_is_bf = (ws_size >= need_bf) ? 1 : 0;
  float* nga_f32 = o_pna;   // fallback: f32 logits staged in d_out, K4 in-place

  k0_scan<<<1, 64, 0, stream>>>(n_nodes, seg_start, G);
  k0_detect<<<1, 256, 0, stream>>>((const unsigned int*)action_mask, GA / 4, mkind);
  k0_pack<<<320, 256, 0, stream>>>(w_node, W_agn, W_nga, W_qna, W_qan, Wpack);
  k1_gemm<<<N / 64, 256, 0, stream>>>(values, Wpack, b_agn, b_nga, b_qna, b_qan,
                                      agn, nga_bf, nga_f32, qna, qan, nl, nga_is_bf);
  k2_segment<<<G, 1024, 0, stream>>>(agn, nga_bf, nga_f32, qna, qan, nl, seg_start,
                                     action_mask, mkind, o_pa, o_entropy, o_value,
                                     Su, nga_is_bf);
  k3_logprob<<<1, 256, 0, stream>>>(o_pa, nga_bf, nga_f32, indices, a_action, a_node,
                                    action_mask, mkind, n_nodes, Su, o_logprob, G,
                                    nga_is_bf);
  if (nga_is_bf)
    k4_pna_bf<<<(N * 8 + 255) / 256, 256, 0, stream>>>(nga_bf, indices, Su, o_pna, N);
  else
    k4_pna_f32<<<(N * 16 + 255) / 256, 256, 0, stream>>>(o_pna, indices, Su, N);
}

// Round 5
// 135.577 us; speedup vs baseline: 1.1128x; 1.0317x over previous
//
#include <hip/hip_runtime.h>
#include <hip/hip_bf16.h>

typedef unsigned short u16;
typedef unsigned int u32;
typedef __attribute__((ext_vector_type(4))) float f32x4;
typedef __attribute__((ext_vector_type(8))) short s16x8;
typedef __attribute__((ext_vector_type(8))) unsigned short u16x8;

#define EPS_V (1e-10f)

__device__ __forceinline__ u16 f2bf(float f) {   // RNE (epilogue only)
  unsigned u = __float_as_uint(f);
  u += 0x7fffu + ((u >> 16) & 1u);
  return (u16)(u >> 16);
}
__device__ __forceinline__ float bf2f(u16 h) {
  return __uint_as_float(((unsigned)h) << 16);
}
__device__ __forceinline__ float wred_sum(float v) {
#pragma unroll
  for (int o = 32; o; o >>= 1) v += __shfl_xor(v, o);
  return v;
}
// mask accessor robust to int32 / float32 / byte storage of the bool mask
__device__ __forceinline__ bool mask_at(const void* m, int kind, int idx) {
  if (kind == 0) return ((const int*)m)[idx] != 0;
  if (kind == 1) return ((const float*)m)[idx] != 0.0f;
  return ((const unsigned char*)m)[idx] != 0;
}

// ---------- K0 fused prologue: block 0 = scan, block 1 = mask-detect,
// blocks 2..321 = weight pack, blocks 322.. = zero q_a ----------
__global__ __launch_bounds__(256) void k0_fused(
    const int* __restrict__ n_nodes, const unsigned int* __restrict__ mask_raw,
    const float* __restrict__ w_node, const float* __restrict__ W_agn,
    const float* __restrict__ W_nga, const float* __restrict__ W_qna,
    const float* __restrict__ W_qan,
    int* __restrict__ seg_start, int* __restrict__ mkind,
    float* __restrict__ q_a, u16* __restrict__ Wpack, int G, int ndw) {
  const int b = blockIdx.x;
  const int t = threadIdx.x;
  if (b == 0) {
    // wave-parallel exclusive scan: lane handles 4 segments
    if (t < 64) {
      int base = t * 4;
      int v0 = (base + 0 < G) ? n_nodes[base + 0] : 0;
      int v1 = (base + 1 < G) ? n_nodes[base + 1] : 0;
      int v2 = (base + 2 < G) ? n_nodes[base + 2] : 0;
      int v3 = (base + 3 < G) ? n_nodes[base + 3] : 0;
      int lsum = v0 + v1 + v2 + v3;
      int x = lsum;
#pragma unroll
      for (int o = 1; o < 64; o <<= 1) {
        int y = __shfl_up(x, o);
        if (t >= o) x += y;
      }
      int run = x - lsum;  // exclusive prefix
      if (base + 0 < G) seg_start[base + 0] = run; run += v0;
      if (base + 1 < G) seg_start[base + 1] = run; run += v1;
      if (base + 2 < G) seg_start[base + 2] = run; run += v2;
      if (base + 3 < G) seg_start[base + 3] = run; run += v3;
      if (t == 63) seg_start[G] = run;
    }
  } else if (b == 1) {
    __shared__ int notInt, notFloat;
    if (t == 0) { notInt = 0; notFloat = 0; }
    __syncthreads();
    int li = 0, lf = 0;
    for (int i = t; i < ndw; i += 256) {
      unsigned v = mask_raw[i];
      if (v != 0u && v != 1u) li = 1;
      if (v != 0u && v != 0x3F800000u) lf = 1;
    }
    if (li) atomicOr(&notInt, 1);
    if (lf) atomicOr(&notFloat, 1);
    __syncthreads();
    if (t == 0) mkind[0] = (!notInt) ? 0 : ((!notFloat) ? 1 : 2);
  } else if (b < 2 + 320) {
    int idx = (b - 2) * 256 + t;  // < 320*256
    int col = idx >> 8, k = idx & 255;
    float v = 0.f;
    if (col < 64) v = W_agn[col * 256 + k];
    else if (col < 128) v = W_nga[(col - 64) * 256 + k];
    else if (col < 192) v = W_qna[(col - 128) * 256 + k];
    else if (col < 256) v = W_qan[(col - 192) * 256 + k];
    else if (col == 256) v = w_node[k];
    Wpack[idx] = f2bf(v);
  } else {
    int idx = (b - 322) * 256 + t;
    if (idx < G * 64) q_a[idx] = 0.f;
  }
}

// fragment: 8 bf16 of row m, k = k0..k0+7, from fp32 LDS with 16B-granule
// XOR-(m&7) swizzle; truncating convert via v_perm (1 op / 2 elems)
__device__ __forceinline__ s16x8 frag_from_lds(const float* Vf, int m, int k0) {
  int g0 = ((k0 >> 2) ^ (m & 7));      // k0>>2 is even
  int g1 = g0 ^ 1;
  const f32x4 lo = *reinterpret_cast<const f32x4*>(&Vf[m * 256 + g0 * 4]);
  const f32x4 hi = *reinterpret_cast<const f32x4*>(&Vf[m * 256 + g1 * 4]);
  union { s16x8 v; u32 u[4]; } r;
  r.u[0] = __builtin_amdgcn_perm(__float_as_uint(lo[1]), __float_as_uint(lo[0]), 0x07060302u);
  r.u[1] = __builtin_amdgcn_perm(__float_as_uint(lo[3]), __float_as_uint(lo[2]), 0x07060302u);
  r.u[2] = __builtin_amdgcn_perm(__float_as_uint(hi[1]), __float_as_uint(hi[0]), 0x07060302u);
  r.u[3] = __builtin_amdgcn_perm(__float_as_uint(hi[3]), __float_as_uint(hi[2]), 0x07060302u);
  return r.v;
}

// ---------- K1: tall GEMM. A staged fp32 via global_load_lds (async, 0 VGPR);
// B direct from L2; qan chunk reduced in-register -> atomicAdd q_a. ----------
__global__ __launch_bounds__(256, 2) void k1_gemm(
    const float* __restrict__ values, const u16* __restrict__ Wpack,
    const int* __restrict__ indices,
    const float* __restrict__ b_agn, const float* __restrict__ b_nga,
    const float* __restrict__ b_qna, const float* __restrict__ b_qan,
    u16* __restrict__ agn, u16* __restrict__ nga_bf, float* __restrict__ nga_f32,
    u16* __restrict__ qna, float* __restrict__ q_a,
    float* __restrict__ nl, int nga_is_bf) {
  __shared__ float Vf[64 * 256];   // 64 KB fp32 tile, granule-swizzled
  __shared__ int seg_ids[64];
  const int t = threadIdx.x;
  const int lane = t & 63;
  const int wave = t >> 6;
  const int row0 = blockIdx.x * 64;

  if (t < 64) seg_ids[t] = indices[row0 + t];

  // async stage: one instr moves 64 lanes x 16B = one fp32 row; dest linear,
  // SOURCE granule XOR-swizzled (rule: swizzle source+read, never the dest)
#pragma unroll
  for (int it = 0; it < 16; ++it) {
    int m = wave * 16 + it;
    const float* gp = values + (size_t)(row0 + m) * 256 + ((lane ^ (m & 7)) << 2);
    __builtin_amdgcn_global_load_lds(
        (const __attribute__((address_space(1))) void*)gp,
        (__attribute__((address_space(3))) void*)&Vf[m * 256], 16, 0, 0);
  }
  __syncthreads();   // drains vmcnt; the only barrier

  const int ln15 = lane & 15;
  const int kg = lane >> 4;
  const int ncol = wave * 16;
  const u16* wbase = Wpack + (size_t)(ncol + ln15) * 256 + kg * 8;

  f32x4 acc[4][4];
#pragma unroll
  for (int c = 0; c < 4; ++c)
#pragma unroll
    for (int mf = 0; mf < 4; ++mf) acc[c][mf] = (f32x4){0.f, 0.f, 0.f, 0.f};

#pragma unroll 2
  for (int s = 0; s < 8; ++s) {
    const int k0 = s * 32 + kg * 8;
    s16x8 a[4];
#pragma unroll
    for (int mf = 0; mf < 4; ++mf) a[mf] = frag_from_lds(Vf, mf * 16 + ln15, k0);
#pragma unroll
    for (int c = 0; c < 4; ++c) {
      s16x8 bfr = *reinterpret_cast<const s16x8*>(wbase + (size_t)c * 16384 + s * 32);
#pragma unroll
      for (int mf = 0; mf < 4; ++mf)
        acc[c][mf] = __builtin_amdgcn_mfma_f32_16x16x32_bf16(a[mf], bfr, acc[c][mf], 0, 0, 0);
    }
  }

  // epilogue: C/D map col = lane&15, row = (lane>>4)*4 + reg  [m89/m91]
  const int cl = ncol + ln15;
  // chunks 0..2 -> stores
#pragma unroll
  for (int c = 0; c < 3; ++c) {
    const float* bias = (c == 0) ? b_agn : (c == 1) ? b_nga : b_qna;
    float bv = bias[cl];
    if (c == 1 && !nga_is_bf) {
#pragma unroll
      for (int mf = 0; mf < 4; ++mf)
#pragma unroll
        for (int r = 0; r < 4; ++r) {
          int m = mf * 16 + kg * 4 + r;
          nga_f32[(size_t)(row0 + m) * 64 + cl] = acc[c][mf][r] + bv;
        }
    } else {
      u16* dst = (c == 0) ? agn : (c == 1) ? nga_bf : qna;
#pragma unroll
      for (int mf = 0; mf < 4; ++mf)
#pragma unroll
        for (int r = 0; r < 4; ++r) {
          int m = mf * 16 + kg * 4 + r;
          dst[(size_t)(row0 + m) * 64 + cl] = f2bf(acc[c][mf][r] + bv);
        }
    }
  }
  // chunk 3 (qan): per-segment-run local sum -> atomicAdd q_a[g][cl]
  {
    float bv = b_qan[cl];
    int cur_g = seg_ids[kg * 4];
    float part = 0.f;
#pragma unroll
    for (int mf = 0; mf < 4; ++mf)
#pragma unroll
      for (int r = 0; r < 4; ++r) {
        int m = mf * 16 + kg * 4 + r;   // monotone in (mf,r)
        int gg = seg_ids[m];
        float v = acc[3][mf][r] + bv;
        if (gg != cur_g) { atomicAdd(&q_a[cur_g * 64 + cl], part); part = 0.f; cur_g = gg; }
        part += v;
      }
    atomicAdd(&q_a[cur_g * 64 + cl], part);
  }

  // node-logit column (global col 256): wave 0 only
  if (wave == 0) {
    f32x4 an[4];
#pragma unroll
    for (int mf = 0; mf < 4; ++mf) an[mf] = (f32x4){0.f, 0.f, 0.f, 0.f};
#pragma unroll 2
    for (int s = 0; s < 8; ++s) {
      const int k0 = s * 32 + kg * 8;
      s16x8 bfr = *reinterpret_cast<const s16x8*>(wbase + (size_t)4 * 16384 + s * 32);
#pragma unroll
      for (int mf = 0; mf < 4; ++mf) {
        s16x8 a = frag_from_lds(Vf, mf * 16 + ln15, k0);
        an[mf] = __builtin_amdgcn_mfma_f32_16x16x32_bf16(a, bfr, an[mf], 0, 0, 0);
      }
    }
    if (ln15 == 0) {
#pragma unroll
      for (int mf = 0; mf < 4; ++mf)
#pragma unroll
        for (int r = 0; r < 4; ++r)
          nl[row0 + mf * 16 + kg * 4 + r] = an[mf][r];
    }
  }
}

// ---------- K2: one block per segment. No-max softmax (logits bounded ~±2). ----------
__global__ __launch_bounds__(1024) void k2_segment(
    const u16* __restrict__ agn, const u16* __restrict__ nga_bf,
    const float* __restrict__ nga_f32, const u16* __restrict__ qna,
    const float* __restrict__ nl, const int* __restrict__ seg_start,
    const void* __restrict__ mask, const int* __restrict__ mkind,
    const float* __restrict__ q_a,
    float* __restrict__ p_a, float* __restrict__ entropy, float* __restrict__ value,
    float* __restrict__ Su, int nga_is_bf) {
  const int g = blockIdx.x;
  const int s = seg_start[g], e = seg_start[g + 1];
  const int n = e - s;
  const int t = threadIdx.x, lane = t & 63, wave = t >> 6;

  __shared__ float wbuf[16];
  __shared__ float cs[16][64], cv[16][64], ci[16][64], cp[16][64];

  // phase A: Sn = sum exp(nl) over segment
  float ls = 0.f;
  for (int i = s + t; i < e; i += 1024) ls += __expf(nl[i]);
  ls = wred_sum(ls);
  if (lane == 0) wbuf[wave] = ls;
  __syncthreads();
  float Sn = 0.f;
#pragma unroll
  for (int w = 0; w < 16; ++w) Sn += wbuf[w];
  float invSn = (Sn > 0.f) ? 1.f / Sn : 0.f;

  // phase B: wave-per-node stream. lane = action.
  const int kind = mkind[0];
  const bool mv = mask_at(mask, kind, g * 64 + lane);
  float s_u = 0.f, v_u = 0.f, i_u = 0.f, pa = 0.f;
  for (int i = s + wave; i < e; i += 16) {
    size_t base = (size_t)i * 64 + lane;
    float pn = __expf(nl[i]) * invSn;
    float ev = mv ? __expf(bf2f(agn[base])) : 0.f;
    float rs = wred_sum(ev);
    pa += pn * ((rs > 0.f) ? ev / rs : 0.015625f);  // all-masked row -> uniform 1/64
    float y = nga_is_bf ? bf2f(nga_bf[base]) : nga_f32[base];
    float ey = __expf(y);
    s_u += ey;
    v_u += ey * y;
    i_u += ey * bf2f(qna[base]);
  }
  cs[wave][lane] = s_u; cv[wave][lane] = v_u; ci[wave][lane] = i_u;
  cp[wave][lane] = pa;
  __syncthreads();

  if (t < 64) {
    int a = t;
    float S = 0.f, V = 0.f, I = 0.f, P = 0.f;
#pragma unroll
    for (int w = 0; w < 16; ++w) {
      S += cs[w][a]; V += cv[w][a]; I += ci[w][a]; P += cp[w][a];
    }
    p_a[g * 64 + a] = P;
    Su[g * 64 + a] = S;
    float inner = (S > 0.f) ? I / S : 0.f;
    float Q = q_a[g * 64 + a];
    bool mva = mask_at(mask, kind, g * 64 + a);
    float Hn;
    if (n <= 0) Hn = 0.f;
    else if (!mva) Hn = -logf(1.0f / (float)n + EPS_V);   // uniform over segment
    else Hn = (S > 0.f) ? (logf(S) - V / S) : 0.f;
    float ent_c = -P * logf(P + EPS_V) + P * Hn;
    float val_c = P * (Q + inner);
    ent_c = wred_sum(ent_c);
    val_c = wred_sum(val_c);
    if (a == 0) { entropy[g] = ent_c; value[g] = val_c; }
  }
}

// ---------- K3: logprob ----------
__global__ __launch_bounds__(256) void k3_logprob(
    const float* __restrict__ p_a, const u16* __restrict__ nga_bf,
    const float* __restrict__ nga_f32, const int* __restrict__ indices,
    const int* __restrict__ a_action, const int* __restrict__ a_node,
    const void* __restrict__ mask, const int* __restrict__ mkind,
    const int* __restrict__ n_nodes, const float* __restrict__ Su,
    float* __restrict__ logprob, int G, int nga_is_bf) {
  int g = blockIdx.x * blockDim.x + threadIdx.x;
  if (g >= G) return;
  int kind = mkind[0];
  int a = a_action[g];
  float t1 = logf(p_a[g * 64 + a] + EPS_V);
  int node = a_node[g];
  int g2 = indices[node];
  float p2;
  if (mask_at(mask, kind, g2 * 64 + a)) {
    float S = Su[g2 * 64 + a];
    float y = nga_is_bf ? bf2f(nga_bf[(size_t)node * 64 + a]) : nga_f32[(size_t)node * 64 + a];
    p2 = (S > 0.f) ? __expf(y) / S : 0.f;
  } else {
    p2 = 1.0f / (float)n_nodes[g2];
  }
  logprob[g] = t1 + logf(p2 + EPS_V);
}

// ---------- K4 (bf16 path): p_n__a = exp(y)/Su, 8 elems/thread ----------
__global__ __launch_bounds__(256) void k4_pna_bf(
    const u16* __restrict__ nga_bf, const int* __restrict__ indices,
    const float* __restrict__ Su, float* __restrict__ pna, int N) {
  int e8 = blockIdx.x * 256 + threadIdx.x;
  if (e8 >= N * 8) return;
  int i = e8 >> 3, a0 = (e8 & 7) * 8;
  int g = indices[i];
  u16x8 y = *reinterpret_cast<const u16x8*>(nga_bf + (size_t)i * 64 + a0);
  float4 S0 = *reinterpret_cast<const float4*>(Su + g * 64 + a0);
  float4 S1 = *reinterpret_cast<const float4*>(Su + g * 64 + a0 + 4);
  float4 o0, o1;
  o0.x = __expf(bf2f(y[0])) / S0.x; o0.y = __expf(bf2f(y[1])) / S0.y;
  o0.z = __expf(bf2f(y[2])) / S0.z; o0.w = __expf(bf2f(y[3])) / S0.w;
  o1.x = __expf(bf2f(y[4])) / S1.x; o1.y = __expf(bf2f(y[5])) / S1.y;
  o1.z = __expf(bf2f(y[6])) / S1.z; o1.w = __expf(bf2f(y[7])) / S1.w;
  float4* dst = reinterpret_cast<float4*>(pna + (size_t)i * 64 + a0);
  dst[0] = o0; dst[1] = o1;
}

// ---------- K4 (f32 fallback, in-place): p = exp(x)/Su ----------
__global__ __launch_bounds__(256) void k4_pna_f32(
    float* __restrict__ pna, const int* __restrict__ indices,
    const float* __restrict__ Su, int N) {
  int e4 = blockIdx.x * 256 + threadIdx.x;
  if (e4 >= N * 16) return;
  int i = e4 >> 4, a0 = (e4 & 15) * 4;
  int g = indices[i];
  float4* p = reinterpret_cast<float4*>(pna + (size_t)i * 64 + a0);
  float4 x = *p;
  float4 S = *reinterpret_cast<const float4*>(Su + g * 64 + a0);
  float4 o;
  o.x = __expf(x.x) / S.x; o.y = __expf(x.y) / S.y;
  o.z = __expf(x.z) / S.z; o.w = __expf(x.w) / S.w;
  *p = o;
}

extern "C" void kernel_launch(void* const* d_in, const int* in_sizes, int n_in,
                              void* d_out, int out_size, void* d_ws, size_t ws_size,
                              hipStream_t stream) {
  const float* values = (const float*)d_in[0];
  const int* indices = (const int*)d_in[1];
  const int* a_action = (const int*)d_in[2];
  const int* a_node = (const int*)d_in[3];
  const void* action_mask = d_in[4];
  const int* n_nodes = (const int*)d_in[5];
  const float* w_node = (const float*)d_in[6];
  const float* W_agn = (const float*)d_in[7];
  const float* b_agn = (const float*)d_in[8];
  const float* W_nga = (const float*)d_in[9];
  const float* b_nga = (const float*)d_in[10];
  const float* W_qna = (const float*)d_in[11];
  const float* b_qna = (const float*)d_in[12];
  const float* W_qan = (const float*)d_in[13];
  const float* b_qan = (const float*)d_in[14];

  const int N = in_sizes[1];   // 131072
  const int G = in_sizes[2];   // 256
  const int GA = in_sizes[4];  // G*64

  float* out = (float*)d_out;
  float* o_logprob = out;
  float* o_entropy = out + G;
  float* o_value = out + 2 * G;
  float* o_pa = out + 3 * G;
  float* o_pna = out + 3 * G + GA;

  char* w = (char*)d_ws;
  size_t off = 0;
  u16* agn = (u16*)(w + off); off += (size_t)N * 64 * 2;
  u16* qna = (u16*)(w + off); off += (size_t)N * 64 * 2;
  float* nl = (float*)(w + off); off += (size_t)N * 4;
  float* Su = (float*)(w + off); off += (size_t)GA * 4;
  float* q_a = (float*)(w + off); off += (size_t)GA * 4;
  int* seg_start = (int*)(w + off); off += (size_t)(G + 1) * 4;
  int* mkind = (int*)(w + off); off += 256;
  off = (off + 255) & ~(size_t)255;
  u16* Wpack = (u16*)(w + off); off += (size_t)320 * 256 * 2;
  u16* nga_bf = (u16*)(w + off);
  size_t need_bf = off + (size_t)N * 64 * 2;
  int nga_is_bf = (ws_size >= need_bf) ? 1 : 0;
  float* nga_f32 = o_pna;   // fallback: f32 logits staged in d_out, K4 in-place

  int zero_blocks = (GA + 255) / 256;
  k0_fused<<<2 + 320 + zero_blocks, 256, 0, stream>>>(
      n_nodes, (const unsigned int*)action_mask, w_node, W_agn, W_nga, W_qna, W_qan,
      seg_start, mkind, q_a, Wpack, G, GA / 4);
  k1_gemm<<<N / 64, 256, 0, stream>>>(values, Wpack, indices,
                                      b_agn, b_nga, b_qna, b_qan,
                                      agn, nga_bf, nga_f32, qna, q_a, nl, nga_is_bf);
  k2_segment<<<G, 1024, 0, stream>>>(agn, nga_bf, nga_f32, qna, nl, seg_start,
                                     action_mask, mkind, q_a,
                                     o_pa, o_entropy, o_value, Su, nga_is_bf);
  k3_logprob<<<(G + 255) / 256, 256, 0, stream>>>(
      o_pa, nga_bf, nga_f32, indices, a_action, a_node,
      action_mask, mkind, n_nodes, Su, o_logprob, G, nga_is_bf);
  if (nga_is_bf)
    k4_pna_bf<<<(N * 8 + 255) / 256, 256, 0, stream>>>(nga_bf, indices, Su, o_pna, N);
  else
    k4_pna_f32<<<(N * 16 + 255) / 256, 256, 0, stream>>>(o_pna, indices, Su, N);
}